// Round 3
// baseline (9945.499 us; speedup 1.0000x reference)
//
#include <hip/hip_runtime.h>

namespace {

constexpr int kB = 512, kD = 64, kP = 16, kT = 500, kH = 128;
constexpr int kRows = 16;            // batch rows per wave (one MFMA tile)
constexpr int kBlocks = kB / kRows;  // 32 blocks, 1 wave each, no intra-step barriers
constexpr int kThreads = 64;

// Dynamic LDS: 80 read-only weight fragments (64 lanes x 8 shorts each)
// + bias arrays. Linear lane*16B layout -> conflict-free ds_read_b128.
// Frag map: 0..15 W0z-lo (T*2+kt), 16..23 W0p-hi (T), 24..31 W0p-lo (T),
//           32..63 W1-lo (32+T*4+kt), 64..79 W2-lo (64+T*4+kt)
constexpr int kFS = 512;                     // shorts per fragment
constexpr int kNFrag = 80;
constexpr int kBiasOff = kNFrag * kFS * 2;   // 81920 bytes
constexpr int kDynLds = kBiasOff + 320 * 4;  // + b0[128], b1[128], b2[64] = 83200

typedef __attribute__((ext_vector_type(8))) short short8;
typedef __attribute__((ext_vector_type(4))) float float4v;

__device__ __forceinline__ float bf2f(unsigned short u) {
  union { unsigned int i; float f; } v;
  v.i = ((unsigned int)u) << 16;
  return v.f;
}
__device__ __forceinline__ unsigned short f2bf(float f) {  // RNE
  union { float f; unsigned int i; } v;
  v.f = f;
  return (unsigned short)((v.i + 0x7FFFu + ((v.i >> 16) & 1u)) >> 16);
}
__device__ __forceinline__ void split_bf(float x, unsigned short& hi, unsigned short& lo) {
  hi = f2bf(x);
  lo = f2bf(x - bf2f(hi));
}
#if __has_builtin(__builtin_amdgcn_cvt_pk_bf16_f32)
__device__ __forceinline__ unsigned int pk_bf16(float a, float b) {
  auto v = __builtin_amdgcn_cvt_pk_bf16_f32(a, b);
  unsigned int u;
  __builtin_memcpy(&u, &v, 4);
  return u;
}
#else
__device__ __forceinline__ unsigned int pk_bf16(float a, float b) {
  return (unsigned int)f2bf(a) | ((unsigned int)f2bf(b) << 16);
}
#endif
// split a pair (a,b) into packed bf16 hi word + lo word
__device__ __forceinline__ void sp2(float a, float b, unsigned int& hw, unsigned int& lw) {
  unsigned int uh = pk_bf16(a, b);
  float ah, bh;
  { unsigned int t1 = uh << 16; __builtin_memcpy(&ah, &t1, 4); }
  { unsigned int t2 = uh & 0xFFFF0000u; __builtin_memcpy(&bh, &t2, 4); }
  hw = uh;
  lw = pk_bf16(a - ah, b - bh);
}
__device__ __forceinline__ short8 mk8(unsigned int a, unsigned int b, unsigned int c,
                                      unsigned int d) {
  union { unsigned int w[4]; short8 s; } u;
  u.w[0] = a; u.w[1] = b; u.w[2] = c; u.w[3] = d;
  return u.s;
}
__device__ __forceinline__ float fast_tanh(float x) {
  // 1 - 2/(e^{2x}+1): exact saturation both ends, no NaN.
  float e = __builtin_amdgcn_exp2f(x * 2.885390081777927f);  // 2*log2(e)
  return 1.0f - 2.0f * __builtin_amdgcn_rcpf(e + 1.0f);
}

#define MFMA(a, b, c) __builtin_amdgcn_mfma_f32_16x16x32_bf16((a), (b), (c), 0, 0, 0)
#define RD(fi) (*(const short8*)&dynS[(fi) * kFS + lane8])

// Transposed-MFMA formulation: A = W^T tile (hi in VGPR/AGPR, lo in LDS),
// B = activations^T (batch row = lane&15), D[hidden][row].
// Tile T covers hidden cols n(T,m) = 32*(T>>1) + 8*(m>>2) + 4*(T&1) + (m&3).
// Producer D-cell (T=2kt+(j>=4), reg=j&3) of layer L sits on EXACTLY the lane
// that needs it as B-frag element (kt, j) of layer L+1 -> handoff is pure
// register repacking. No LDS round-trip for activations, no __syncthreads in
// the 500-step loop. This round: register-economy fix (round 2 spilled).
__global__ __launch_bounds__(kThreads, 1) void node_kernel(
    const float* __restrict__ xg, const float* __restrict__ pg,
    const float* __restrict__ w0g, const float* __restrict__ b0g,
    const float* __restrict__ w1g, const float* __restrict__ b1g,
    const float* __restrict__ w2g, const float* __restrict__ b2g,
    float* __restrict__ outg) {
  extern __shared__ char dynraw[];
  short* dynS = (short*)dynraw;
  float* bflds = (float*)(dynraw + kBiasOff);

  const int lane = threadIdx.x & 63;
  const int l15 = lane & 15;
  const int q = lane >> 4;
  const int lane8 = lane * 8;
  const int brow = blockIdx.x * kRows;

  // ---- persistent hi-weight A-fragments (64 frags = 256 regs, MFMA-only use
  // -> AV-class, expect AGPR placement); all lo + W0p to LDS ----
  short8 w0h[8][2], w1h[8][4], w2h[4][4];
#pragma unroll
  for (int T = 0; T < 8; ++T) {
    const int nW = 32 * (T >> 1) + 8 * (l15 >> 2) + 4 * (T & 1) + (l15 & 3);
#pragma unroll
    for (int kt = 0; kt < 2; ++kt) {  // W0 state part (k 0..63)
      short8 vh, vl;
#pragma unroll
      for (int j = 0; j < 8; ++j) {
        unsigned short hi, lo;
        split_bf(w0g[(kt * 32 + q * 8 + j) * kH + nW], hi, lo);
        vh[j] = (short)hi; vl[j] = (short)lo;
      }
      w0h[T][kt] = vh;
      *(short8*)&dynS[(T * 2 + kt) * kFS + lane8] = vl;
    }
    {  // W0 p part (k 64..79, zero-padded to 96) -> LDS (hi and lo)
      short8 vh, vl;
#pragma unroll
      for (int j = 0; j < 8; ++j) {
        int k = 64 + q * 8 + j;
        unsigned short hi = 0, lo = 0;
        if (k < 80) split_bf(w0g[k * kH + nW], hi, lo);
        vh[j] = (short)hi; vl[j] = (short)lo;
      }
      *(short8*)&dynS[(16 + T) * kFS + lane8] = vh;
      *(short8*)&dynS[(24 + T) * kFS + lane8] = vl;
    }
#pragma unroll
    for (int kt = 0; kt < 4; ++kt) {  // W1
      short8 vh, vl;
#pragma unroll
      for (int j = 0; j < 8; ++j) {
        unsigned short hi, lo;
        split_bf(w1g[(kt * 32 + q * 8 + j) * kH + nW], hi, lo);
        vh[j] = (short)hi; vl[j] = (short)lo;
      }
      w1h[T][kt] = vh;
      *(short8*)&dynS[(32 + T * 4 + kt) * kFS + lane8] = vl;
    }
  }
#pragma unroll
  for (int T = 0; T < 4; ++T) {  // W2 (64 output cols)
    const int nW = 32 * (T >> 1) + 8 * (l15 >> 2) + 4 * (T & 1) + (l15 & 3);
#pragma unroll
    for (int kt = 0; kt < 4; ++kt) {
      short8 vh, vl;
#pragma unroll
      for (int j = 0; j < 8; ++j) {
        unsigned short hi, lo;
        split_bf(w2g[(kt * 32 + q * 8 + j) * kD + nW], hi, lo);
        vh[j] = (short)hi; vl[j] = (short)lo;
      }
      w2h[T][kt] = vh;
      *(short8*)&dynS[(64 + T * 4 + kt) * kFS + lane8] = vl;
    }
  }
  // biases
  for (int i = lane; i < 128; i += 64) {
    bflds[i] = b0g[i];
    bflds[128 + i] = b1g[i];
  }
  bflds[256 + lane] = b2g[lane];

  // ---- lane-local fp32 state: lane(q,l15) holds rows l15, d = n(T, q*4+r) ----
  float stv[16];
#pragma unroll
  for (int T = 0; T < 4; ++T)
#pragma unroll
    for (int r = 0; r < 4; ++r)
      stv[T * 4 + r] =
          xg[((size_t)(brow + l15) * kD + (32 * (T >> 1) + 8 * q + 4 * (T & 1) + r)) * kT];

  const float* prow = pg + ((size_t)(brow + l15) * kP + q * 8) * kT;  // valid q<2
  float pcur[8];
#pragma unroll
  for (int j = 0; j < 8; ++j) pcur[j] = 0.f;
  if (q < 2) {
#pragma unroll
    for (int j = 0; j < 8; ++j) pcur[j] = prow[j * kT];
  }
  float* orow = outg + ((size_t)(brow + l15) * kD + q * 8) * kT;

  __syncthreads();  // the only barrier: LDS weight images ready

  const int bq = 8 * q;

  short8 zfh[2], zfl[2];  // state B-fragments (hi/lo split); live build->L0 only
  auto buildz = [&](const float* v) {
#pragma unroll
    for (int kt = 0; kt < 2; ++kt) {
      unsigned int hw[4], lw[4];
#pragma unroll
      for (int u = 0; u < 4; ++u) {
        int Ta = 2 * kt + (u >> 1), bb = u & 1;
        sp2(v[Ta * 4 + 2 * bb], v[Ta * 4 + 2 * bb + 1], hw[u], lw[u]);
      }
      zfh[kt] = mk8(hw[0], hw[1], hw[2], hw[3]);
      zfl[kt] = mk8(lw[0], lw[1], lw[2], lw[3]);
    }
  };
  buildz(stv);

  for (int t = 0; t < kT; ++t) {
    // p B-fragments for this step (zero on lanes q>=2 via pcur=0)
    short8 zph, zpl;
    {
      unsigned int hw[4], lw[4];
#pragma unroll
      for (int u = 0; u < 4; ++u) sp2(pcur[2 * u], pcur[2 * u + 1], hw[u], lw[u]);
      zph = mk8(hw[0], hw[1], hw[2], hw[3]);
      zpl = mk8(lw[0], lw[1], lw[2], lw[3]);
    }
    // prefetch p(t+1); latency hides under the evals
    float pnx[8];
#pragma unroll
    for (int j = 0; j < 8; ++j) pnx[j] = 0.f;
    if (q < 2 && t + 1 < kT) {
#pragma unroll
      for (int j = 0; j < 8; ++j) pnx[j] = prow[j * kT + (t + 1)];
    }

    float d1v[16];
#pragma unroll
    for (int ev = 0; ev < 2; ++ev) {
      // ---- L0: D = W0^T z^T, p-term folded as 3rd k-chain; fully chained ----
      short8 h0f[4];
#pragma unroll
      for (int kt = 0; kt < 4; ++kt) {
        unsigned int w[4];
#pragma unroll
        for (int hf = 0; hf < 2; ++hf) {
          const int T = 2 * kt + hf;
          float4v ac = *(const float4v*)&bflds[32 * (T >> 1) + bq + 4 * (T & 1)];
          short8 wph = RD(16 + T);
          ac = MFMA(w0h[T][0], zfh[0], ac);
          ac = MFMA(w0h[T][1], zfh[1], ac);
          ac = MFMA(wph, zph, ac);
          ac = MFMA(w0h[T][0], zfl[0], ac);
          ac = MFMA(w0h[T][1], zfl[1], ac);
          ac = MFMA(wph, zpl, ac);
          ac = MFMA(RD(T * 2), zfh[0], ac);
          ac = MFMA(RD(T * 2 + 1), zfh[1], ac);
          ac = MFMA(RD(24 + T), zph, ac);
          w[hf * 2 + 0] = pk_bf16(fast_tanh(ac[0]), fast_tanh(ac[1]));
          w[hf * 2 + 1] = pk_bf16(fast_tanh(ac[2]), fast_tanh(ac[3]));
        }
        h0f[kt] = mk8(w[0], w[1], w[2], w[3]);
      }
      // ---- L1: hi-activation + w-lo correction, fully chained ----
      short8 h1f[4];
#pragma unroll
      for (int kt = 0; kt < 4; ++kt) {
        unsigned int w[4];
#pragma unroll
        for (int hf = 0; hf < 2; ++hf) {
          const int T = 2 * kt + hf;
          float4v ac = *(const float4v*)&bflds[128 + 32 * (T >> 1) + bq + 4 * (T & 1)];
          ac = MFMA(w1h[T][0], h0f[0], ac);
          ac = MFMA(w1h[T][1], h0f[1], ac);
          ac = MFMA(w1h[T][2], h0f[2], ac);
          ac = MFMA(w1h[T][3], h0f[3], ac);
          ac = MFMA(RD(32 + T * 4 + 0), h0f[0], ac);
          ac = MFMA(RD(32 + T * 4 + 1), h0f[1], ac);
          ac = MFMA(RD(32 + T * 4 + 2), h0f[2], ac);
          ac = MFMA(RD(32 + T * 4 + 3), h0f[3], ac);
          w[hf * 2 + 0] = pk_bf16(fast_tanh(ac[0]), fast_tanh(ac[1]));
          w[hf * 2 + 1] = pk_bf16(fast_tanh(ac[2]), fast_tanh(ac[3]));
        }
        h1f[kt] = mk8(w[0], w[1], w[2], w[3]);
      }
      // ---- L2, fully chained ----
      float a2[16];
#pragma unroll
      for (int T = 0; T < 4; ++T) {
        float4v ac = *(const float4v*)&bflds[256 + 32 * (T >> 1) + bq + 4 * (T & 1)];
        ac = MFMA(w2h[T][0], h1f[0], ac);
        ac = MFMA(w2h[T][1], h1f[1], ac);
        ac = MFMA(w2h[T][2], h1f[2], ac);
        ac = MFMA(w2h[T][3], h1f[3], ac);
        ac = MFMA(RD(64 + T * 4 + 0), h1f[0], ac);
        ac = MFMA(RD(64 + T * 4 + 1), h1f[1], ac);
        ac = MFMA(RD(64 + T * 4 + 2), h1f[2], ac);
        ac = MFMA(RD(64 + T * 4 + 3), h1f[3], ac);
#pragma unroll
        for (int r = 0; r < 4; ++r) a2[T * 4 + r] = ac[r];
      }
      // ---- Heun update (all lane-local) ----
      if (ev == 0) {
        float xiv[16];  // transient: dead after buildz
#pragma unroll
        for (int i2 = 0; i2 < 16; ++i2) {
          d1v[i2] = a2[i2];
          xiv[i2] = stv[i2] + a2[i2];  // dt = 1
        }
        buildz(xiv);
      } else {
#pragma unroll
        for (int T = 0; T < 4; ++T)
#pragma unroll
          for (int r = 0; r < 4; ++r)  // emit PREVIOUS state
            orow[((T >> 1) * 32 + (T & 1) * 4 + r) * kT + t] = stv[T * 4 + r];
#pragma unroll
        for (int i2 = 0; i2 < 16; ++i2) stv[i2] = stv[i2] + 0.5f * (a2[i2] + d1v[i2]);
        buildz(stv);
      }
    }
#pragma unroll
    for (int j = 0; j < 8; ++j) pcur[j] = pnx[j];
  }
}

}  // namespace

extern "C" void kernel_launch(void* const* d_in, const int* in_sizes, int n_in,
                              void* d_out, int out_size, void* d_ws, size_t ws_size,
                              hipStream_t stream) {
  const float* xg = (const float*)d_in[0];   // x [512,64,500]
  const float* pg = (const float*)d_in[1];   // p [512,16,500]
  // d_in[2] = i_ext (unused by Simple_MLP)
  const float* w0g = (const float*)d_in[3];  // W0 [80,128]
  const float* b0g = (const float*)d_in[4];  // b0 [128]
  const float* w1g = (const float*)d_in[5];  // W1 [128,128]
  const float* b1g = (const float*)d_in[6];  // b1 [128]
  const float* w2g = (const float*)d_in[7];  // W2 [128,64]
  const float* b2g = (const float*)d_in[8];  // b2 [64]
  float* outg = (float*)d_out;               // [512,64,500] fp32

  static bool attr_done = false;
  if (!attr_done) {
    hipFuncSetAttribute(reinterpret_cast<const void*>(node_kernel),
                        hipFuncAttributeMaxDynamicSharedMemorySize, kDynLds);
    attr_done = true;
  }
  hipLaunchKernelGGL(node_kernel, dim3(kBlocks), dim3(kThreads), kDynLds, stream,
                     xg, pg, w0g, b0g, w1g, b1g, w2g, b2g, outg);
}

// Round 4
// 8808.479 us; speedup vs baseline: 1.1291x; 1.1291x over previous
//
#include <hip/hip_runtime.h>

namespace {

constexpr int kB = 512, kD = 64, kP = 16, kT = 500, kH = 128;
constexpr int kRows = 16;            // batch rows per wave (one MFMA tile)
constexpr int kBlocks = kB / kRows;  // 32 blocks, 1 wave each, no intra-step barriers
constexpr int kThreads = 64;

// Dynamic LDS: 80 read-only weight fragments (64 lanes x 8 shorts each)
// + bias arrays. Linear lane*16B layout -> conflict-free ds_read_b128.
// Frag map: 0..15 W0z-lo (T*2+kt), 16..23 W0p-hi (T), 24..31 W0p-lo (T),
//           32..63 W1-lo (32+T*4+kt), 64..79 W2-lo (64+T*4+kt)
constexpr int kFS = 512;                     // shorts per fragment
constexpr int kNFrag = 80;
constexpr int kBiasOff = kNFrag * kFS * 2;   // 81920 bytes
constexpr int kDynLds = kBiasOff + 320 * 4;  // + b0[128], b1[128], b2[64] = 83200

typedef __attribute__((ext_vector_type(8))) short short8;
typedef __attribute__((ext_vector_type(4))) float float4v;
typedef __attribute__((ext_vector_type(2))) float float2v;

__device__ __forceinline__ float bf2f(unsigned short u) {
  union { unsigned int i; float f; } v;
  v.i = ((unsigned int)u) << 16;
  return v.f;
}
__device__ __forceinline__ unsigned short f2bf(float f) {  // RNE
  union { float f; unsigned int i; } v;
  v.f = f;
  return (unsigned short)((v.i + 0x7FFFu + ((v.i >> 16) & 1u)) >> 16);
}
__device__ __forceinline__ void split_bf(float x, unsigned short& hi, unsigned short& lo) {
  hi = f2bf(x);
  lo = f2bf(x - bf2f(hi));
}
#if __has_builtin(__builtin_amdgcn_cvt_pk_bf16_f32)
__device__ __forceinline__ unsigned int pk_bf16(float a, float b) {
  auto v = __builtin_amdgcn_cvt_pk_bf16_f32(a, b);
  unsigned int u;
  __builtin_memcpy(&u, &v, 4);
  return u;
}
#else
__device__ __forceinline__ unsigned int pk_bf16(float a, float b) {
  return (unsigned int)f2bf(a) | ((unsigned int)f2bf(b) << 16);
}
#endif
// split a pair (a,b) into packed bf16 hi word + lo word
__device__ __forceinline__ void sp2(float a, float b, unsigned int& hw, unsigned int& lw) {
  unsigned int uh = pk_bf16(a, b);
  float ah, bh;
  { unsigned int t1 = uh << 16; __builtin_memcpy(&ah, &t1, 4); }
  { unsigned int t2 = uh & 0xFFFF0000u; __builtin_memcpy(&bh, &t2, 4); }
  hw = uh;
  lw = pk_bf16(a - ah, b - bh);
}
__device__ __forceinline__ short8 mk8(unsigned int a, unsigned int b, unsigned int c,
                                      unsigned int d) {
  union { unsigned int w[4]; short8 s; } u;
  u.w[0] = a; u.w[1] = b; u.w[2] = c; u.w[3] = d;
  return u.s;
}
__device__ __forceinline__ float fast_tanh(float x) {
  // 1 - 2/(e^{2x}+1): exact saturation both ends, no NaN.
  float e = __builtin_amdgcn_exp2f(x * 2.885390081777927f);  // 2*log2(e)
  return 1.0f - 2.0f * __builtin_amdgcn_rcpf(e + 1.0f);
}

#define MFMA(a, b, c) __builtin_amdgcn_mfma_f32_16x16x32_bf16((a), (b), (c), 0, 0, 0)
#define RD(fi) (*(const short8*)&dynS[(fi) * kFS + lane8])

// Transposed-MFMA formulation: A = W^T tile (hi pinned in AGPR, lo in LDS),
// B = activations^T (batch row = lane&15), D[hidden][row].
// Tile T covers hidden cols n(T,m) = 32*(T>>1) + 8*(m>>2) + 4*(T&1) + (m&3).
// Producer D-cell (T=2kt+(j>=4), reg=j&3) of layer L sits on EXACTLY the lane
// that needs it as B-frag element (kt, j) of layer L+1 -> handoff is pure
// register repacking. No LDS round-trip for activations, no __syncthreads in
// the 500-step loop. This round: pin the 64 hi-weight frags (256 regs) into
// AGPRs via empty asm "+a" class pins -> arch-VGPR demand drops under the 256
// cap -> no scratch spill (rounds 2/3 spilled ~75MB/dispatch).
__global__ __launch_bounds__(kThreads, 1) void node_kernel(
    const float* __restrict__ xg, const float* __restrict__ pg,
    const float* __restrict__ w0g, const float* __restrict__ b0g,
    const float* __restrict__ w1g, const float* __restrict__ b1g,
    const float* __restrict__ w2g, const float* __restrict__ b2g,
    float* __restrict__ outg) {
  extern __shared__ char dynraw[];
  short* dynS = (short*)dynraw;
  float* bflds = (float*)(dynraw + kBiasOff);

  const int lane = threadIdx.x & 63;
  const int l15 = lane & 15;
  const int q = lane >> 4;
  const int lane8 = lane * 8;
  const int brow = blockIdx.x * kRows;

  // ---- persistent hi-weight A-fragments (64 frags = 256 AGPRs); lo -> LDS ----
  short8 w0h[8][2], w1h[8][4], w2h[4][4];
#pragma unroll
  for (int T = 0; T < 8; ++T) {
    const int nW = 32 * (T >> 1) + 8 * (l15 >> 2) + 4 * (T & 1) + (l15 & 3);
#pragma unroll
    for (int kt = 0; kt < 2; ++kt) {  // W0 state part (k 0..63)
      short8 vh, vl;
#pragma unroll
      for (int j = 0; j < 8; ++j) {
        unsigned short hi, lo;
        split_bf(w0g[(kt * 32 + q * 8 + j) * kH + nW], hi, lo);
        vh[j] = (short)hi; vl[j] = (short)lo;
      }
      w0h[T][kt] = vh;
      *(short8*)&dynS[(T * 2 + kt) * kFS + lane8] = vl;
    }
    {  // W0 p part (k 64..79, zero-padded to 96) -> LDS (hi and lo)
      short8 vh, vl;
#pragma unroll
      for (int j = 0; j < 8; ++j) {
        int k = 64 + q * 8 + j;
        unsigned short hi = 0, lo = 0;
        if (k < 80) split_bf(w0g[k * kH + nW], hi, lo);
        vh[j] = (short)hi; vl[j] = (short)lo;
      }
      *(short8*)&dynS[(16 + T) * kFS + lane8] = vh;
      *(short8*)&dynS[(24 + T) * kFS + lane8] = vl;
    }
#pragma unroll
    for (int kt = 0; kt < 4; ++kt) {  // W1
      short8 vh, vl;
#pragma unroll
      for (int j = 0; j < 8; ++j) {
        unsigned short hi, lo;
        split_bf(w1g[(kt * 32 + q * 8 + j) * kH + nW], hi, lo);
        vh[j] = (short)hi; vl[j] = (short)lo;
      }
      w1h[T][kt] = vh;
      *(short8*)&dynS[(32 + T * 4 + kt) * kFS + lane8] = vl;
    }
  }
#pragma unroll
  for (int T = 0; T < 4; ++T) {  // W2 (64 output cols)
    const int nW = 32 * (T >> 1) + 8 * (l15 >> 2) + 4 * (T & 1) + (l15 & 3);
#pragma unroll
    for (int kt = 0; kt < 4; ++kt) {
      short8 vh, vl;
#pragma unroll
      for (int j = 0; j < 8; ++j) {
        unsigned short hi, lo;
        split_bf(w2g[(kt * 32 + q * 8 + j) * kD + nW], hi, lo);
        vh[j] = (short)hi; vl[j] = (short)lo;
      }
      w2h[T][kt] = vh;
      *(short8*)&dynS[(64 + T * 4 + kt) * kFS + lane8] = vl;
    }
  }
  // ---- pin hi-weight frags into AGPR class (zero-instruction re-def) ----
  // All subsequent uses are MFMA A-operands (AV-class) -> they live in AGPRs
  // for the whole loop, freeing the arch-VGPR file for the working set.
#pragma unroll
  for (int T = 0; T < 8; ++T) {
    asm("" : "+a"(w0h[T][0]), "+a"(w0h[T][1]));
    asm("" : "+a"(w1h[T][0]), "+a"(w1h[T][1]), "+a"(w1h[T][2]), "+a"(w1h[T][3]));
  }
#pragma unroll
  for (int T = 0; T < 4; ++T)
    asm("" : "+a"(w2h[T][0]), "+a"(w2h[T][1]), "+a"(w2h[T][2]), "+a"(w2h[T][3]));

  // biases
  for (int i = lane; i < 128; i += 64) {
    bflds[i] = b0g[i];
    bflds[128 + i] = b1g[i];
  }
  bflds[256 + lane] = b2g[lane];

  // ---- lane-local fp32 state: lane(q,l15) holds rows l15, d = n(T, q*4+r) ----
  float stv[16];
#pragma unroll
  for (int T = 0; T < 4; ++T)
#pragma unroll
    for (int r = 0; r < 4; ++r)
      stv[T * 4 + r] =
          xg[((size_t)(brow + l15) * kD + (32 * (T >> 1) + 8 * q + 4 * (T & 1) + r)) * kT];

  const float* prow = pg + ((size_t)(brow + l15) * kP + q * 8) * kT;  // valid q<2
  float pcur[8];
#pragma unroll
  for (int j = 0; j < 8; ++j) pcur[j] = 0.f;
  if (q < 2) {
#pragma unroll
    for (int j = 0; j < 8; ++j) pcur[j] = prow[j * kT];
  }
  float* orow = outg + ((size_t)(brow + l15) * kD + q * 8) * kT;

  __syncthreads();  // the only barrier: LDS weight images ready

  const int bq = 8 * q;

  short8 zfh[2], zfl[2];  // state B-fragments (hi/lo split)
  auto buildz = [&](const float* v) {
#pragma unroll
    for (int kt = 0; kt < 2; ++kt) {
      unsigned int hw[4], lw[4];
#pragma unroll
      for (int u = 0; u < 4; ++u) {
        int Ta = 2 * kt + (u >> 1), bb = u & 1;
        sp2(v[Ta * 4 + 2 * bb], v[Ta * 4 + 2 * bb + 1], hw[u], lw[u]);
      }
      zfh[kt] = mk8(hw[0], hw[1], hw[2], hw[3]);
      zfl[kt] = mk8(lw[0], lw[1], lw[2], lw[3]);
    }
  };
  buildz(stv);

  float yst[16];  // even-step output stage (paired dwordx2 stores)

  for (int t = 0; t < kT; ++t) {
    // p B-fragments for this step (zero on lanes q>=2 via pcur=0)
    short8 zph, zpl;
    {
      unsigned int hw[4], lw[4];
#pragma unroll
      for (int u = 0; u < 4; ++u) sp2(pcur[2 * u], pcur[2 * u + 1], hw[u], lw[u]);
      zph = mk8(hw[0], hw[1], hw[2], hw[3]);
      zpl = mk8(lw[0], lw[1], lw[2], lw[3]);
    }
    // step-invariant p-term (+bias0), cached across both Heun evals
    float4v psum[8];
#pragma unroll
    for (int T = 0; T < 8; ++T) {
      float4v s = *(const float4v*)&bflds[32 * (T >> 1) + bq + 4 * (T & 1)];
      short8 wph = RD(16 + T);
      s = MFMA(wph, zph, s);
      s = MFMA(wph, zpl, s);
      s = MFMA(RD(24 + T), zph, s);
      psum[T] = s;
    }
    // prefetch p(t+1); latency hides under the evals
    float pnx[8];
#pragma unroll
    for (int j = 0; j < 8; ++j) pnx[j] = 0.f;
    if (q < 2 && t + 1 < kT) {
#pragma unroll
      for (int j = 0; j < 8; ++j) pnx[j] = prow[j * kT + (t + 1)];
    }

    float d1v[16];
#pragma unroll
    for (int ev = 0; ev < 2; ++ev) {
      // ---- L0: D = W0^T z^T (+psum); AGPR-hi first, LDS-lo last ----
      short8 h0f[4];
#pragma unroll
      for (int kt = 0; kt < 4; ++kt) {
        unsigned int w[4];
#pragma unroll
        for (int hf = 0; hf < 2; ++hf) {
          const int T = 2 * kt + hf;
          float4v ac = psum[T];
          ac = MFMA(w0h[T][0], zfh[0], ac);
          ac = MFMA(w0h[T][1], zfh[1], ac);
          ac = MFMA(w0h[T][0], zfl[0], ac);
          ac = MFMA(w0h[T][1], zfl[1], ac);
          ac = MFMA(RD(T * 2), zfh[0], ac);
          ac = MFMA(RD(T * 2 + 1), zfh[1], ac);
          w[hf * 2 + 0] = pk_bf16(fast_tanh(ac[0]), fast_tanh(ac[1]));
          w[hf * 2 + 1] = pk_bf16(fast_tanh(ac[2]), fast_tanh(ac[3]));
        }
        h0f[kt] = mk8(w[0], w[1], w[2], w[3]);
      }
      // ---- L1: hi-activation chain + w-lo correction ----
      short8 h1f[4];
#pragma unroll
      for (int kt = 0; kt < 4; ++kt) {
        unsigned int w[4];
#pragma unroll
        for (int hf = 0; hf < 2; ++hf) {
          const int T = 2 * kt + hf;
          float4v ac = *(const float4v*)&bflds[128 + 32 * (T >> 1) + bq + 4 * (T & 1)];
          ac = MFMA(w1h[T][0], h0f[0], ac);
          ac = MFMA(w1h[T][1], h0f[1], ac);
          ac = MFMA(w1h[T][2], h0f[2], ac);
          ac = MFMA(w1h[T][3], h0f[3], ac);
          ac = MFMA(RD(32 + T * 4 + 0), h0f[0], ac);
          ac = MFMA(RD(32 + T * 4 + 1), h0f[1], ac);
          ac = MFMA(RD(32 + T * 4 + 2), h0f[2], ac);
          ac = MFMA(RD(32 + T * 4 + 3), h0f[3], ac);
          w[hf * 2 + 0] = pk_bf16(fast_tanh(ac[0]), fast_tanh(ac[1]));
          w[hf * 2 + 1] = pk_bf16(fast_tanh(ac[2]), fast_tanh(ac[3]));
        }
        h1f[kt] = mk8(w[0], w[1], w[2], w[3]);
      }
      // ---- L2 ----
      float a2[16];
#pragma unroll
      for (int T = 0; T < 4; ++T) {
        float4v ac = *(const float4v*)&bflds[256 + 32 * (T >> 1) + bq + 4 * (T & 1)];
        ac = MFMA(w2h[T][0], h1f[0], ac);
        ac = MFMA(w2h[T][1], h1f[1], ac);
        ac = MFMA(w2h[T][2], h1f[2], ac);
        ac = MFMA(w2h[T][3], h1f[3], ac);
        ac = MFMA(RD(64 + T * 4 + 0), h1f[0], ac);
        ac = MFMA(RD(64 + T * 4 + 1), h1f[1], ac);
        ac = MFMA(RD(64 + T * 4 + 2), h1f[2], ac);
        ac = MFMA(RD(64 + T * 4 + 3), h1f[3], ac);
#pragma unroll
        for (int r = 0; r < 4; ++r) a2[T * 4 + r] = ac[r];
      }
      // ---- Heun update (all lane-local) ----
      if (ev == 0) {
        float xiv[16];  // transient: dead after buildz
#pragma unroll
        for (int i2 = 0; i2 < 16; ++i2) {
          d1v[i2] = a2[i2];
          xiv[i2] = stv[i2] + a2[i2];  // dt = 1
        }
        buildz(xiv);
      } else {
        // emit PREVIOUS state; pair even/odd t into 8B stores
        if ((t & 1) == 0) {
#pragma unroll
          for (int i2 = 0; i2 < 16; ++i2) yst[i2] = stv[i2];
        } else {
#pragma unroll
          for (int T = 0; T < 4; ++T)
#pragma unroll
            for (int r = 0; r < 4; ++r) {
              const int i2 = T * 4 + r;
              const int d = (T >> 1) * 32 + (T & 1) * 4 + r;
              float2v v2 = {yst[i2], stv[i2]};
              *(float2v*)&orow[d * kT + (t - 1)] = v2;
            }
        }
#pragma unroll
        for (int i2 = 0; i2 < 16; ++i2) stv[i2] = stv[i2] + 0.5f * (a2[i2] + d1v[i2]);
        buildz(stv);
      }
    }
#pragma unroll
    for (int j = 0; j < 8; ++j) pcur[j] = pnx[j];
  }
}

}  // namespace

extern "C" void kernel_launch(void* const* d_in, const int* in_sizes, int n_in,
                              void* d_out, int out_size, void* d_ws, size_t ws_size,
                              hipStream_t stream) {
  const float* xg = (const float*)d_in[0];   // x [512,64,500]
  const float* pg = (const float*)d_in[1];   // p [512,16,500]
  // d_in[2] = i_ext (unused by Simple_MLP)
  const float* w0g = (const float*)d_in[3];  // W0 [80,128]
  const float* b0g = (const float*)d_in[4];  // b0 [128]
  const float* w1g = (const float*)d_in[5];  // W1 [128,128]
  const float* b1g = (const float*)d_in[6];  // b1 [128]
  const float* w2g = (const float*)d_in[7];  // W2 [128,64]
  const float* b2g = (const float*)d_in[8];  // b2 [64]
  float* outg = (float*)d_out;               // [512,64,500] fp32

  static bool attr_done = false;
  if (!attr_done) {
    hipFuncSetAttribute(reinterpret_cast<const void*>(node_kernel),
                        hipFuncAttributeMaxDynamicSharedMemorySize, kDynLds);
    attr_done = true;
  }
  hipLaunchKernelGGL(node_kernel, dim3(kBlocks), dim3(kThreads), kDynLds, stream,
                     xg, pg, w0g, b0g, w1g, b1g, w2g, b2g, outg);
}

// Round 6
// 3612.904 us; speedup vs baseline: 2.7528x; 2.4381x over previous
//
#include <hip/hip_runtime.h>

namespace {

constexpr int kB = 512, kD = 64, kP = 16, kT = 500, kH = 128;
constexpr int kRows = 16;            // batch rows per wave (one MFMA tile)
constexpr int kBlocks = kB / kRows;  // 32 blocks, 1 wave each, no intra-step barriers
constexpr int kThreads = 64;

// Dynamic LDS: ALL 144 split-weight fragments (64 lanes x 8 shorts = 1KB each)
// + bias arrays. Linear lane*16B layout -> conflict-free ds_read_b128.
// Abs frag map:
//   0..31   W1-hi  (T*4+kt)          region0 rel T*4+kt
//   32..63  W1-lo  (32+T*4+kt)       region0 rel 32+T*4+kt
//   64..79  W0z-hi (64+T*2+kt)       region1 rel T*2+kt
//   80..95  W0z-lo                   region1 rel 16+T*2+kt
//   96..103 W0p-hi                   region1 rel 32+T
//  104..111 W0p-lo                   region1 rel 40+T
//  112..127 W2-hi                    region1 rel 48+T*4+kt
//  128..143 W2-lo                    region2 rel T*4+kt
constexpr int kFS = 512;                     // shorts per fragment
constexpr int kNFrag = 144;
constexpr int kBiasOff = kNFrag * kFS * 2;   // 147456 bytes
constexpr int kDynLds = kBiasOff + 320 * 4;  // + b0[128], b1[128], b2[64] = 148736

typedef __attribute__((ext_vector_type(8))) short short8;
typedef __attribute__((ext_vector_type(4))) float float4v;

__device__ __forceinline__ float bf2f(unsigned short u) {
  union { unsigned int i; float f; } v;
  v.i = ((unsigned int)u) << 16;
  return v.f;
}
__device__ __forceinline__ unsigned short f2bf(float f) {  // RNE
  union { float f; unsigned int i; } v;
  v.f = f;
  return (unsigned short)((v.i + 0x7FFFu + ((v.i >> 16) & 1u)) >> 16);
}
__device__ __forceinline__ void split_bf(float x, unsigned short& hi, unsigned short& lo) {
  hi = f2bf(x);
  lo = f2bf(x - bf2f(hi));
}
#if __has_builtin(__builtin_amdgcn_cvt_pk_bf16_f32)
__device__ __forceinline__ unsigned int pk_bf16(float a, float b) {
  auto v = __builtin_amdgcn_cvt_pk_bf16_f32(a, b);
  unsigned int u;
  __builtin_memcpy(&u, &v, 4);
  return u;
}
#else
__device__ __forceinline__ unsigned int pk_bf16(float a, float b) {
  return (unsigned int)f2bf(a) | ((unsigned int)f2bf(b) << 16);
}
#endif
// split a pair (a,b) into packed bf16 hi word + lo word
__device__ __forceinline__ void sp2(float a, float b, unsigned int& hw, unsigned int& lw) {
  unsigned int uh = pk_bf16(a, b);
  float ah, bh;
  { unsigned int t1 = uh << 16; __builtin_memcpy(&ah, &t1, 4); }
  { unsigned int t2 = uh & 0xFFFF0000u; __builtin_memcpy(&bh, &t2, 4); }
  hw = uh;
  lw = pk_bf16(a - ah, b - bh);
}
__device__ __forceinline__ short8 mk8(unsigned int a, unsigned int b, unsigned int c,
                                      unsigned int d) {
  union { unsigned int w[4]; short8 s; } u;
  u.w[0] = a; u.w[1] = b; u.w[2] = c; u.w[3] = d;
  return u.s;
}
__device__ __forceinline__ float fast_tanh(float x) {
  // 1 - 2/(e^{2x}+1): exact saturation both ends, no NaN.
  float e = __builtin_amdgcn_exp2f(x * 2.885390081777927f);  // 2*log2(e)
  return 1.0f - 2.0f * __builtin_amdgcn_rcpf(e + 1.0f);
}

#define MFMA(a, b, c) __builtin_amdgcn_mfma_f32_16x16x32_bf16((a), (b), (c), 0, 0, 0)

// Transposed-MFMA formulation: A = W^T tile (ALL weights in LDS this round),
// B = activations^T (batch row = lane&15), D[hidden][row].
// Tile T covers hidden cols n(T,m) = 32*(T>>1) + 8*(m>>2) + 4*(T&1) + (m&3).
// Producer D-cell (T=2kt+(j>=4), reg=j&3) of layer L sits on EXACTLY the lane
// that needs it as B-frag element (kt, j) of layer L+1 -> handoff is pure
// register repacking. No LDS round-trip for activations, no __syncthreads in
// the 500-step loop. Rounds 2-4 showed 256 weight regs cannot fit -> spill;
// this round weights live in LDS and obscured offsets (asm "+v") stop LLVM
// from hoisting the loop-invariant ds_reads back into registers.
__global__ __launch_bounds__(kThreads, 1) void node_kernel(
    const float* __restrict__ xg, const float* __restrict__ pg,
    const float* __restrict__ w0g, const float* __restrict__ b0g,
    const float* __restrict__ w1g, const float* __restrict__ b1g,
    const float* __restrict__ w2g, const float* __restrict__ b2g,
    float* __restrict__ outg) {
  extern __shared__ char dynraw[];
  short* dynS = (short*)dynraw;
  float* bflds = (float*)(dynraw + kBiasOff);

  const int lane = threadIdx.x & 63;
  const int l15 = lane & 15;
  const int q = lane >> 4;
  const int lane8 = lane * 8;
  const int brow = blockIdx.x * kRows;

  // ---- stage ALL split-weight fragments (hi and lo) into LDS ----
#pragma unroll
  for (int T = 0; T < 8; ++T) {
    const int nW = 32 * (T >> 1) + 8 * (l15 >> 2) + 4 * (T & 1) + (l15 & 3);
#pragma unroll
    for (int kt = 0; kt < 2; ++kt) {  // W0 state part (k 0..63)
      short8 vh, vl;
#pragma unroll
      for (int j = 0; j < 8; ++j) {
        unsigned short hi, lo;
        split_bf(w0g[(kt * 32 + q * 8 + j) * kH + nW], hi, lo);
        vh[j] = (short)hi; vl[j] = (short)lo;
      }
      *(short8*)&dynS[(64 + T * 2 + kt) * kFS + lane8] = vh;
      *(short8*)&dynS[(80 + T * 2 + kt) * kFS + lane8] = vl;
    }
    {  // W0 p part (k 64..79, zero-padded to 96)
      short8 vh, vl;
#pragma unroll
      for (int j = 0; j < 8; ++j) {
        int k = 64 + q * 8 + j;
        unsigned short hi = 0, lo = 0;
        if (k < 80) split_bf(w0g[k * kH + nW], hi, lo);
        vh[j] = (short)hi; vl[j] = (short)lo;
      }
      *(short8*)&dynS[(96 + T) * kFS + lane8] = vh;
      *(short8*)&dynS[(104 + T) * kFS + lane8] = vl;
    }
#pragma unroll
    for (int kt = 0; kt < 4; ++kt) {  // W1
      short8 vh, vl;
#pragma unroll
      for (int j = 0; j < 8; ++j) {
        unsigned short hi, lo;
        split_bf(w1g[(kt * 32 + q * 8 + j) * kH + nW], hi, lo);
        vh[j] = (short)hi; vl[j] = (short)lo;
      }
      *(short8*)&dynS[(T * 4 + kt) * kFS + lane8] = vh;
      *(short8*)&dynS[(32 + T * 4 + kt) * kFS + lane8] = vl;
    }
  }
#pragma unroll
  for (int T = 0; T < 4; ++T) {  // W2 (64 output cols)
    const int nW = 32 * (T >> 1) + 8 * (l15 >> 2) + 4 * (T & 1) + (l15 & 3);
#pragma unroll
    for (int kt = 0; kt < 4; ++kt) {
      short8 vh, vl;
#pragma unroll
      for (int j = 0; j < 8; ++j) {
        unsigned short hi, lo;
        split_bf(w2g[(kt * 32 + q * 8 + j) * kD + nW], hi, lo);
        vh[j] = (short)hi; vl[j] = (short)lo;
      }
      *(short8*)&dynS[(112 + T * 4 + kt) * kFS + lane8] = vh;
      *(short8*)&dynS[(128 + T * 4 + kt) * kFS + lane8] = vl;
    }
  }
  // biases
  for (int i = lane; i < 128; i += 64) {
    bflds[i] = b0g[i];
    bflds[128 + i] = b1g[i];
  }
  bflds[256 + lane] = b2g[lane];

  // ---- lane-local fp32 state: lane(q,l15) holds rows l15, d = n(T, q*4+r) ----
  float stv[16];
#pragma unroll
  for (int T = 0; T < 4; ++T)
#pragma unroll
    for (int r = 0; r < 4; ++r)
      stv[T * 4 + r] =
          xg[((size_t)(brow + l15) * kD + (32 * (T >> 1) + 8 * q + 4 * (T & 1) + r)) * kT];

  const float* prow = pg + ((size_t)(brow + l15) * kP + q * 8) * kT;  // valid q<2
  float pcur[8];
#pragma unroll
  for (int j = 0; j < 8; ++j) pcur[j] = 0.f;
  if (q < 2) {
#pragma unroll
    for (int j = 0; j < 8; ++j) pcur[j] = prow[j * kT];
  }
  float* orow = outg + ((size_t)(brow + l15) * kD + q * 8) * kT;

  __syncthreads();  // LDS weight images ready (single wave: also a waitcnt fence)

  const int bq = 8 * q;

  // Obscured LDS offsets: values are compile-time known but the asm pins make
  // them opaque per t-iteration and per Heun-eval, so the (store-free) weight
  // loads cannot be hoisted/CSE'd into long-lived registers. Base stays AS3
  // -> still ds_read_b128 with immediate offsets (each region < 64KB).
  unsigned wo0 = 0;             // region0: frags 0..63   (W1 hi/lo)
  unsigned wo1 = 64u * kFS;     // region1: frags 64..127 (W0z, W0p, W2-hi)
  unsigned wo2 = 128u * kFS;    // region2: frags 128..143 (W2-lo)
  unsigned wob = kBiasOff / 2;  // biases (float region, short-indexed base)

#define RD0(rel) (*(const short8*)&dynS[wo0 + (rel) * kFS + lane8])
#define RD1(rel) (*(const short8*)&dynS[wo1 + (rel) * kFS + lane8])
#define RD2(rel) (*(const short8*)&dynS[wo2 + (rel) * kFS + lane8])
#define BIAS4(i) (*(const float4v*)&((const float*)&dynS[wob])[(i)])
#define BIDX(T) (32 * ((T) >> 1) + bq + 4 * ((T)&1))

  short8 zfh[2], zfl[2];  // state B-fragments (hi/lo split)
  auto buildz = [&](const float* v) {
#pragma unroll
    for (int kt = 0; kt < 2; ++kt) {
      unsigned int hw[4], lw[4];
#pragma unroll
      for (int u = 0; u < 4; ++u) {
        int Ta = 2 * kt + (u >> 1), bb = u & 1;
        sp2(v[Ta * 4 + 2 * bb], v[Ta * 4 + 2 * bb + 1], hw[u], lw[u]);
      }
      zfh[kt] = mk8(hw[0], hw[1], hw[2], hw[3]);
      zfl[kt] = mk8(lw[0], lw[1], lw[2], lw[3]);
    }
  };
  buildz(stv);

  for (int t = 0; t < kT; ++t) {
    asm("" : "+v"(wo0), "+v"(wo1), "+v"(wo2), "+v"(wob));  // t-scope pin
    // p B-fragments for this step (zero on lanes q>=2 via pcur=0)
    short8 zph, zpl;
    {
      unsigned int hw[4], lw[4];
#pragma unroll
      for (int u = 0; u < 4; ++u) sp2(pcur[2 * u], pcur[2 * u + 1], hw[u], lw[u]);
      zph = mk8(hw[0], hw[1], hw[2], hw[3]);
      zpl = mk8(lw[0], lw[1], lw[2], lw[3]);
    }
    // step-invariant p-term (+bias0), cached across both Heun evals
    float4v psum[8];
#pragma unroll
    for (int T = 0; T < 8; ++T) {
      float4v s = BIAS4(BIDX(T));
      short8 wph = RD1(32 + T);
      s = MFMA(wph, zph, s);
      s = MFMA(wph, zpl, s);
      s = MFMA(RD1(40 + T), zph, s);
      psum[T] = s;
    }
    // prefetch p(t+1); latency hides under the evals
    float pnx[8];
#pragma unroll
    for (int j = 0; j < 8; ++j) pnx[j] = 0.f;
    if (q < 2 && t + 1 < kT) {
#pragma unroll
      for (int j = 0; j < 8; ++j) pnx[j] = prow[j * kT + (t + 1)];
    }

    float d1v[16];
#pragma unroll
    for (int ev = 0; ev < 2; ++ev) {
      asm("" : "+v"(wo0), "+v"(wo1), "+v"(wo2), "+v"(wob));  // eval-scope pin
      // ---- L0: D = W0^T z^T (+psum) ----
      short8 h0f[4];
#pragma unroll
      for (int kt = 0; kt < 4; ++kt) {
        unsigned int w[4];
#pragma unroll
        for (int hf = 0; hf < 2; ++hf) {
          const int T = 2 * kt + hf;
          float4v ac = psum[T];
          short8 wh0 = RD1(T * 2), wh1 = RD1(T * 2 + 1);
          ac = MFMA(wh0, zfh[0], ac);
          ac = MFMA(wh1, zfh[1], ac);
          ac = MFMA(wh0, zfl[0], ac);
          ac = MFMA(wh1, zfl[1], ac);
          ac = MFMA(RD1(16 + T * 2), zfh[0], ac);
          ac = MFMA(RD1(17 + T * 2), zfh[1], ac);
          w[hf * 2 + 0] = pk_bf16(fast_tanh(ac[0]), fast_tanh(ac[1]));
          w[hf * 2 + 1] = pk_bf16(fast_tanh(ac[2]), fast_tanh(ac[3]));
        }
        h0f[kt] = mk8(w[0], w[1], w[2], w[3]);
      }
      // ---- L1: hi-activation chain + w-lo correction ----
      short8 h1f[4];
#pragma unroll
      for (int kt = 0; kt < 4; ++kt) {
        unsigned int w[4];
#pragma unroll
        for (int hf = 0; hf < 2; ++hf) {
          const int T = 2 * kt + hf;
          float4v ac = BIAS4(128 + BIDX(T));
          ac = MFMA(RD0(T * 4 + 0), h0f[0], ac);
          ac = MFMA(RD0(T * 4 + 1), h0f[1], ac);
          ac = MFMA(RD0(T * 4 + 2), h0f[2], ac);
          ac = MFMA(RD0(T * 4 + 3), h0f[3], ac);
          ac = MFMA(RD0(32 + T * 4 + 0), h0f[0], ac);
          ac = MFMA(RD0(32 + T * 4 + 1), h0f[1], ac);
          ac = MFMA(RD0(32 + T * 4 + 2), h0f[2], ac);
          ac = MFMA(RD0(32 + T * 4 + 3), h0f[3], ac);
          w[hf * 2 + 0] = pk_bf16(fast_tanh(ac[0]), fast_tanh(ac[1]));
          w[hf * 2 + 1] = pk_bf16(fast_tanh(ac[2]), fast_tanh(ac[3]));
        }
        h1f[kt] = mk8(w[0], w[1], w[2], w[3]);
      }
      // ---- L2 ----
      float a2[16];
#pragma unroll
      for (int T = 0; T < 4; ++T) {
        float4v ac = BIAS4(256 + BIDX(T));
        ac = MFMA(RD1(48 + T * 4 + 0), h1f[0], ac);
        ac = MFMA(RD1(48 + T * 4 + 1), h1f[1], ac);
        ac = MFMA(RD1(48 + T * 4 + 2), h1f[2], ac);
        ac = MFMA(RD1(48 + T * 4 + 3), h1f[3], ac);
        ac = MFMA(RD2(T * 4 + 0), h1f[0], ac);
        ac = MFMA(RD2(T * 4 + 1), h1f[1], ac);
        ac = MFMA(RD2(T * 4 + 2), h1f[2], ac);
        ac = MFMA(RD2(T * 4 + 3), h1f[3], ac);
#pragma unroll
        for (int r = 0; r < 4; ++r) a2[T * 4 + r] = ac[r];
      }
      // ---- Heun update (all lane-local) ----
      if (ev == 0) {
        float xiv[16];  // transient: dead after buildz
#pragma unroll
        for (int i2 = 0; i2 < 16; ++i2) {
          d1v[i2] = a2[i2];
          xiv[i2] = stv[i2] + a2[i2];  // dt = 1
        }
        buildz(xiv);
      } else {
#pragma unroll
        for (int T = 0; T < 4; ++T)
#pragma unroll
          for (int r = 0; r < 4; ++r)  // emit PREVIOUS state
            orow[((T >> 1) * 32 + (T & 1) * 4 + r) * kT + t] = stv[T * 4 + r];
#pragma unroll
        for (int i2 = 0; i2 < 16; ++i2) stv[i2] = stv[i2] + 0.5f * (a2[i2] + d1v[i2]);
        buildz(stv);
      }
    }
#pragma unroll
    for (int j = 0; j < 8; ++j) pcur[j] = pnx[j];
  }
#undef RD0
#undef RD1
#undef RD2
#undef BIAS4
#undef BIDX
}

}  // namespace

extern "C" void kernel_launch(void* const* d_in, const int* in_sizes, int n_in,
                              void* d_out, int out_size, void* d_ws, size_t ws_size,
                              hipStream_t stream) {
  const float* xg = (const float*)d_in[0];   // x [512,64,500]
  const float* pg = (const float*)d_in[1];   // p [512,16,500]
  // d_in[2] = i_ext (unused by Simple_MLP)
  const float* w0g = (const float*)d_in[3];  // W0 [80,128]
  const float* b0g = (const float*)d_in[4];  // b0 [128]
  const float* w1g = (const float*)d_in[5];  // W1 [128,128]
  const float* b1g = (const float*)d_in[6];  // b1 [128]
  const float* w2g = (const float*)d_in[7];  // W2 [128,64]
  const float* b2g = (const float*)d_in[8];  // b2 [64]
  float* outg = (float*)d_out;               // [512,64,500] fp32

  static bool attr_done = false;
  if (!attr_done) {
    hipFuncSetAttribute(reinterpret_cast<const void*>(node_kernel),
                        hipFuncAttributeMaxDynamicSharedMemorySize, kDynLds);
    attr_done = true;
  }
  hipLaunchKernelGGL(node_kernel, dim3(kBlocks), dim3(kThreads), kDynLds, stream,
                     xg, pg, w0g, b0g, w1g, b1g, w2g, b2g, outg);
}